// Round 2
// baseline (216.188 us; speedup 1.0000x reference)
//
#include <hip/hip_runtime.h>
#include <math.h>

#define O_CH 32
#define I_CH 3
#define IH 512
#define IW 512
#define OH 510
#define OW 510
#define N_IMG 16

#define TW 128          // output tile width
#define TH 8            // output tile height
#define PX 4            // output px per thread (x)
#define TIW (TW + 2)    // 130 input cols needed
#define TIWP 132        // padded LDS row stride (float4-aligned, breaks pow2)
#define TIH (TH + 2)    // 10 input rows needed
#define WSTRIDE 32      // padded weight row stride (128 B -> s_load_dwordx4-friendly)

__global__ __launch_bounds__(256) void gabor_weights_kernel(
    const float* __restrict__ freq, const float* __restrict__ theta,
    const float* __restrict__ psi, const float* __restrict__ sigma,
    float* __restrict__ wp) {
  int idx = blockIdx.x * 256 + threadIdx.x;
  if (idx >= O_CH * I_CH * 9) return;
  int o = idx / 27;
  int rem = idx % 27;          // rem = c*9 + kh*3 + kw
  int c = rem / 9;
  int kh = (rem / 3) % 3;
  int kw = rem % 3;
  // linspace(-ceil(3/2)+1, ceil(3/2), 3) = {-1, 0.5, 2}
  float x = (kw == 0) ? -1.0f : (kw == 1 ? 0.5f : 2.0f);
  float y = (kh == 0) ? -1.0f : (kh == 1 ? 0.5f : 2.0f);
  int pi = o * I_CH + c;       // (O,I) parameter index
  float th = theta[pi], f = freq[pi], p = psi[pi], s = sigma[pi];
  float ct = cosf(th), st = sinf(th);
  float rotx = x * ct + y * st;
  float roty = -x * st + y * ct;
  float se = s + 0.001f;
  float g = expf(-0.5f * (rotx * rotx + roty * roty) / (se * se));
  g *= cosf(f * rotx + p);
  g /= (2.0f * 3.14f * s * s);   // reference uses PI = 3.14 exactly
  wp[o * WSTRIDE + rem] = g;
}

__global__ __launch_bounds__(256) void gabor_conv_kernel(
    const float* __restrict__ in, const float* __restrict__ wgp,
    float* __restrict__ out) {
  __shared__ float sIn[I_CH][TIH][TIWP];

  const int tid = threadIdx.x;
  const int n = blockIdx.z;
  const int ty0 = blockIdx.y * TH;
  const int tx0 = blockIdx.x * TW;

  const float* inN = in + (size_t)n * I_CH * IH * IW;

  // Stage input tile (halo'd, edge-clamped; clamped elems only feed OOB outputs)
  for (int i = tid; i < I_CH * TIH * TIW; i += 256) {
    int col = i % TIW;
    int t = i / TIW;
    int row = t % TIH;
    int c = t / TIH;
    int gr = ty0 + row; if (gr > IH - 1) gr = IH - 1;
    int gc = tx0 + col; if (gc > IW - 1) gc = IW - 1;
    sIn[c][row][col] = inN[(c * IH + gr) * IW + gc];
  }
  __syncthreads();

  const int txi = tid & 31;   // 32 threads across x
  const int tyi = tid >> 5;   // 8 rows
  const int lx = txi * PX;
  const int oy = ty0 + tyi;
  const int ox = tx0 + lx;

  // Input window for 4 output px: 3 ch x 3 rows x 6 cols, in registers
  float r[I_CH][3][6];
#pragma unroll
  for (int c = 0; c < I_CH; ++c) {
#pragma unroll
    for (int kh = 0; kh < 3; ++kh) {
      float4 v = *(const float4*)&sIn[c][tyi + kh][lx];       // 16B-aligned
      float2 u = *(const float2*)&sIn[c][tyi + kh][lx + 4];   // 8B-aligned
      r[c][kh][0] = v.x; r[c][kh][1] = v.y;
      r[c][kh][2] = v.z; r[c][kh][3] = v.w;
      r[c][kh][4] = u.x; r[c][kh][5] = u.y;
    }
  }

  const bool rowOK = (oy < OH);
  float* outN = out + (size_t)n * O_CH * OH * OW;

#pragma unroll 2
  for (int o = 0; o < O_CH; ++o) {
    // Wave-uniform weight reads: address has no threadIdx dependency and
    // __restrict__ proves no alias with `out` -> compiler emits s_load into
    // SGPRs; the FMAs below then use the free SGPR operand slot.
    float wv[27];
#pragma unroll
    for (int k = 0; k < 27; ++k) wv[k] = wgp[o * WSTRIDE + k];

    float a0 = 0.f, a1 = 0.f, a2 = 0.f, a3 = 0.f;
#pragma unroll
    for (int c = 0; c < I_CH; ++c) {
#pragma unroll
      for (int kh = 0; kh < 3; ++kh) {
#pragma unroll
        for (int kw = 0; kw < 3; ++kw) {
          float w = wv[c * 9 + kh * 3 + kw];
          a0 = fmaf(r[c][kh][kw + 0], w, a0);
          a1 = fmaf(r[c][kh][kw + 1], w, a1);
          a2 = fmaf(r[c][kh][kw + 2], w, a2);
          a3 = fmaf(r[c][kh][kw + 3], w, a3);
        }
      }
    }
    if (rowOK) {
      size_t ob = ((size_t)o * OH + oy) * OW + ox;
      if (ox + PX <= OW) {
        // base index is always even -> 8B-aligned float2 stores
        *(float2*)&outN[ob] = make_float2(a0, a1);
        *(float2*)&outN[ob + 2] = make_float2(a2, a3);
      } else {
        if (ox + 0 < OW) outN[ob + 0] = a0;
        if (ox + 1 < OW) outN[ob + 1] = a1;
        if (ox + 2 < OW) outN[ob + 2] = a2;
        if (ox + 3 < OW) outN[ob + 3] = a3;
      }
    }
  }
}

extern "C" void kernel_launch(void* const* d_in, const int* in_sizes, int n_in,
                              void* d_out, int out_size, void* d_ws, size_t ws_size,
                              hipStream_t stream) {
  const float* img   = (const float*)d_in[0];
  const float* freq  = (const float*)d_in[1];
  const float* theta = (const float*)d_in[2];
  const float* psi   = (const float*)d_in[3];
  const float* sigma = (const float*)d_in[4];
  float* outp = (float*)d_out;
  float* wgp = (float*)d_ws;  // 32x32 floats of scratch (padded Gabor weights)

  gabor_weights_kernel<<<dim3(4), dim3(256), 0, stream>>>(freq, theta, psi, sigma, wgp);

  dim3 grid((OW + TW - 1) / TW, (OH + TH - 1) / TH, N_IMG);  // 4 x 64 x 16
  gabor_conv_kernel<<<grid, dim3(256), 0, stream>>>(img, wgp, outp);
}

// Round 3
// 170.154 us; speedup vs baseline: 1.2705x; 1.2705x over previous
//
#include <hip/hip_runtime.h>
#include <math.h>

#define O_CH 32
#define I_CH 3
#define IH 512
#define IW 512
#define OH 510
#define OW 510
#define N_IMG 16
#define WSTRIDE 32       // compact weight row stride in d_ws
#define ROWS_PER_BLOCK 4 // one wave per output row

__global__ __launch_bounds__(256) void gabor_weights_kernel(
    const float* __restrict__ freq, const float* __restrict__ theta,
    const float* __restrict__ psi, const float* __restrict__ sigma,
    float* __restrict__ wp) {
  int idx = blockIdx.x * 256 + threadIdx.x;
  if (idx >= O_CH * I_CH * 9) return;
  int o = idx / 27;
  int rem = idx % 27;          // rem = c*9 + kh*3 + kw
  int kh = (rem / 3) % 3;
  int kw = rem % 3;
  // linspace(-ceil(3/2)+1, ceil(3/2), 3) = {-1, 0.5, 2}
  float x = (kw == 0) ? -1.0f : (kw == 1 ? 0.5f : 2.0f);
  float y = (kh == 0) ? -1.0f : (kh == 1 ? 0.5f : 2.0f);
  int pi = o * I_CH + rem / 9; // (O,I) parameter index
  float th = theta[pi], f = freq[pi], p = psi[pi], s = sigma[pi];
  float ct = cosf(th), st = sinf(th);
  float rotx = x * ct + y * st;
  float roty = -x * st + y * ct;
  float se = s + 0.001f;
  float g = expf(-0.5f * (rotx * rotx + roty * roty) / (se * se));
  g *= cosf(f * rotx + p);
  g /= (2.0f * 3.14f * s * s);   // reference uses PI = 3.14 exactly
  wp[o * WSTRIDE + rem] = g;
}

// One wave == one full output row (510 px) for one (n, y), all 32 o-channels.
// No input LDS, no per-tile barrier: input window lives in 90 VGPRs, weights
// come from a tiny broadcast-LDS table staged once per block.
__global__ __launch_bounds__(256) void gabor_conv_kernel(
    const float* __restrict__ in, const float* __restrict__ wgp,
    float* __restrict__ out) {
  // Weights padded per-channel to 12 floats (stride 48B, float4-aligned rows)
  __shared__ float sW[O_CH][I_CH * 12];

  const int tid = threadIdx.x;
  // stage 32*36 = 1152 floats of weights
  for (int i = tid; i < O_CH * I_CH * 12; i += 256) {
    int o = i / 36;
    int t = i % 36;
    int c = t / 12;
    int j = t % 12;
    sW[o][t] = (j < 9) ? wgp[o * WSTRIDE + c * 9 + j] : 0.0f;
  }
  __syncthreads();

  const int wave = tid >> 6;       // 0..3
  const int lane = tid & 63;
  const int n = blockIdx.y;
  const int y = blockIdx.x * ROWS_PER_BLOCK + wave;   // output row
  const int x0 = lane * 8;         // this lane's first output col

  const float* inN = in + (size_t)n * I_CH * IH * IW;

  // Load input window: 3 ch x 3 rows x 10 cols (cols x0 .. x0+9) into regs.
  float r[I_CH][3][10];
#pragma unroll
  for (int c = 0; c < I_CH; ++c) {
#pragma unroll
    for (int kh = 0; kh < 3; ++kh) {
      int yr = y + kh; if (yr > IH - 1) yr = IH - 1;   // only masked rows clamp
      const float* rowp = inN + (c * IH + yr) * IW;
      float4 A = *(const float4*)&rowp[x0];            // 16B aligned (x0%4==0)
      float4 B = *(const float4*)&rowp[x0 + 4];
      int xc = x0 + 8; if (xc > IW - 4) xc = IW - 4;   // lane63 clamp (junk ok)
      float2 C = *(const float2*)&rowp[xc];
      r[c][kh][0] = A.x; r[c][kh][1] = A.y; r[c][kh][2] = A.z; r[c][kh][3] = A.w;
      r[c][kh][4] = B.x; r[c][kh][5] = B.y; r[c][kh][6] = B.z; r[c][kh][7] = B.w;
      r[c][kh][8] = C.x; r[c][kh][9] = C.y;
    }
  }

  const bool rowOK = (y < OH);
  const bool fullLane = (x0 + 8 <= OW);   // lanes 0..62
  float* outN = out + (size_t)n * O_CH * OH * OW;

  const float4* sW4base = (const float4*)&sW[0][0];

#pragma unroll 2
  for (int o = 0; o < O_CH; ++o) {
    float a0 = 0.f, a1 = 0.f, a2 = 0.f, a3 = 0.f;
    float a4 = 0.f, a5 = 0.f, a6 = 0.f, a7 = 0.f;
#pragma unroll
    for (int c = 0; c < I_CH; ++c) {
      // 12 weights for (o,c): 3 broadcast ds_read_b128 (conflict-free)
      const float4* w4 = sW4base + o * 9 + c * 3;
      float4 w0 = w4[0], w1 = w4[1], w2 = w4[2];
      float wq[9];
      wq[0] = w0.x; wq[1] = w0.y; wq[2] = w0.z; wq[3] = w0.w;
      wq[4] = w1.x; wq[5] = w1.y; wq[6] = w1.z; wq[7] = w1.w;
      wq[8] = w2.x;
#pragma unroll
      for (int kh = 0; kh < 3; ++kh) {
#pragma unroll
        for (int kw = 0; kw < 3; ++kw) {
          float w = wq[kh * 3 + kw];
          a0 = fmaf(r[c][kh][kw + 0], w, a0);
          a1 = fmaf(r[c][kh][kw + 1], w, a1);
          a2 = fmaf(r[c][kh][kw + 2], w, a2);
          a3 = fmaf(r[c][kh][kw + 3], w, a3);
          a4 = fmaf(r[c][kh][kw + 4], w, a4);
          a5 = fmaf(r[c][kh][kw + 5], w, a5);
          a6 = fmaf(r[c][kh][kw + 6], w, a6);
          a7 = fmaf(r[c][kh][kw + 7], w, a7);
        }
      }
    }
    if (rowOK) {
      size_t ob = ((size_t)o * OH + y) * OW + x0;   // always even -> 8B aligned
      float2* q = (float2*)&outN[ob];
      q[0] = make_float2(a0, a1);
      q[1] = make_float2(a2, a3);
      q[2] = make_float2(a4, a5);
      if (fullLane) q[3] = make_float2(a6, a7);
    }
  }
}

extern "C" void kernel_launch(void* const* d_in, const int* in_sizes, int n_in,
                              void* d_out, int out_size, void* d_ws, size_t ws_size,
                              hipStream_t stream) {
  const float* img   = (const float*)d_in[0];
  const float* freq  = (const float*)d_in[1];
  const float* theta = (const float*)d_in[2];
  const float* psi   = (const float*)d_in[3];
  const float* sigma = (const float*)d_in[4];
  float* outp = (float*)d_out;
  float* wgp = (float*)d_ws;  // 32x32 floats of scratch (Gabor weights)

  gabor_weights_kernel<<<dim3(4), dim3(256), 0, stream>>>(freq, theta, psi, sigma, wgp);

  dim3 grid((OH + ROWS_PER_BLOCK - 1) / ROWS_PER_BLOCK, N_IMG);  // 128 x 16
  gabor_conv_kernel<<<grid, dim3(256), 0, stream>>>(img, wgp, outp);
}